// Round 10
// baseline (74.586 us; speedup 1.0000x reference)
//
#include <hip/hip_runtime.h>

#define NFEAT   100000
#define NBATCH  256
#define DIM     128
#define MARGIN_F 0.5f
#define GRID    625                       // blocks; 625*10*16 = 100000 exactly
#define NT      10                        // 16-row feature tiles per block
#define ROWS_PB (NT * 16)                 // 160
#define FLT_BIG 3.402823466e+38f

typedef __bf16 bf8_t  __attribute__((ext_vector_type(8)));
typedef short  sh8_t  __attribute__((ext_vector_type(8)));
typedef float  f32x4  __attribute__((ext_vector_type(4)));

// f32 -> bf16 native cast: compiler emits v_cvt_pk_bf16_f32 pairs (RTNE).
__device__ __forceinline__ bf8_t pack8(float4 v0, float4 v1) {
  bf8_t r;
  r[0] = (__bf16)v0.x; r[1] = (__bf16)v0.y; r[2] = (__bf16)v0.z; r[3] = (__bf16)v0.w;
  r[4] = (__bf16)v1.x; r[5] = (__bf16)v1.y; r[6] = (__bf16)v1.z; r[7] = (__bf16)v1.w;
  return r;
}

// MFMA dispatch: works whether the builtin takes bf16-vectors or short-vectors
template <typename VA, typename VC>
__device__ __forceinline__ auto mfma_sel(VA a, VA b, VC c, int)
    -> decltype(__builtin_amdgcn_mfma_f32_16x16x32_bf16(a, b, c, 0, 0, 0)) {
  return __builtin_amdgcn_mfma_f32_16x16x32_bf16(a, b, c, 0, 0, 0);
}
template <typename VA, typename VC>
__device__ __forceinline__ VC mfma_sel(VA a, VA b, VC c, long) {
  return __builtin_amdgcn_mfma_f32_16x16x32_bf16(
      __builtin_bit_cast(sh8_t, a), __builtin_bit_cast(sh8_t, b), c, 0, 0, 0);
}
__device__ __forceinline__ f32x4 mfma_bf16(bf8_t a, bf8_t b, f32x4 c) {
  return mfma_sel(a, b, c, 0);
}

// Kernel 1: fused GEMM + masked min/max partial reduction.
// R10 change: INDEPENDENT WAVES. No LDS, no barriers (diagnosis: the
// per-iteration 8-wave barrier made load issue bursty -- ~5% memory duty
// cycle, ~430 GB/s sustained = the whole duration). 625 blocks x 4 waves;
// wave w owns batch rows [64w,64w+64) (4 M-tiles); all 4 waves stream the
// SAME 10 contiguous 16-row feature tiles (8 KB each) -- the 4x re-read is
// served by the block's shared L1 (32 KB). B: global->reg->cvt, depth-2
// named-buffer prefetch (static indices, rule #20), labels ride along.
// Waves self-schedule -> continuous load issue from 8 waves/CU.
// MFMA 16x16x32 layouts (guide §3, m89/m91-verified):
//   A: lane l holds A[m0 + (l&15)][k0 + (l>>4)*8 + e]
//   B: lane l holds B[k0 + (l>>4)*8 + e][j0 + (l&15)]   (= features[j][k])
//   D: lane l reg r = sim[m0 + (l>>4)*4 + r][j0 + (l&15)]
__global__ __launch_bounds__(256) void triplet_partial(
    const float* __restrict__ inputs, const float* __restrict__ features,
    const int* __restrict__ targets, const int* __restrict__ flabels,
    const int* __restrict__ idx,
    float* __restrict__ ppos, float* __restrict__ pneg,
    float* __restrict__ out)
{
  const int tid  = threadIdx.x;
  const int lane = tid & 63;
  const int wv   = tid >> 6;      // 0..3
  const int l15  = lane & 15;
  const int lg   = lane >> 4;     // 0..3
  const int m0   = wv * 64;
  const int blk  = blockIdx.x;
  const int rowbase = blk * ROWS_PB;   // first feature row of this block

  if (blk == 0 && tid == 0) out[0] = 0.0f;   // K2 accumulates atomically

  // ---- A fragments first (oldest in vmcnt queue: consuming them leaves the
  // younger tile loads in flight). Pipelined per-M-tile: <=16 float4 live.
  bf8_t afrag[4][4];
  {
    float4 p0[4], p1[4], q0[4], q1[4];
    auto LOADA = [&](int mt, float4 (&v0)[4], float4 (&v1)[4]) {
      const float* ap = inputs + (m0 + mt * 16 + l15) * DIM;
#pragma unroll
      for (int ks = 0; ks < 4; ++ks) {
        const int k = ks * 32 + lg * 8;
        v0[ks] = *reinterpret_cast<const float4*>(ap + k);
        v1[ks] = *reinterpret_cast<const float4*>(ap + k + 4);
      }
    };
    LOADA(0, p0, p1); LOADA(1, q0, q1);
#pragma unroll
    for (int ks = 0; ks < 4; ++ks) afrag[0][ks] = pack8(p0[ks], p1[ks]);
    LOADA(2, p0, p1);
#pragma unroll
    for (int ks = 0; ks < 4; ++ks) afrag[1][ks] = pack8(q0[ks], q1[ks]);
    LOADA(3, q0, q1);
#pragma unroll
    for (int ks = 0; ks < 4; ++ks) afrag[2][ks] = pack8(p0[ks], p1[ks]);
#pragma unroll
    for (int ks = 0; ks < 4; ++ks) afrag[3][ks] = pack8(q0[ks], q1[ks]);
  }

  // packed row metadata: meta = (self_gallery_row << 10) | target_label
  int meta[4][4];
#pragma unroll
  for (int mt = 0; mt < 4; ++mt)
#pragma unroll
    for (int rr = 0; rr < 4; ++rr) {
      const int row = m0 + mt * 16 + lg * 4 + rr;
      meta[mt][rr] = (idx[row] << 10) | targets[row];
    }

  float minpos[4][4], maxneg[4][4];
#pragma unroll
  for (int mt = 0; mt < 4; ++mt)
#pragma unroll
    for (int rr = 0; rr < 4; ++rr) { minpos[mt][rr] = FLT_BIG; maxneg[mt][rr] = -FLT_BIG; }

  // ---- B tile machinery: lane reads features[rowbase + t*16 + l15][k-slice]
  auto LOADT = [&](int t, float4 (&b0)[4], float4 (&b1)[4], int& lab) {
    const int r = rowbase + t * 16 + l15;
    const char* rp = (const char*)features + (size_t)r * 512 + lg * 32;
#pragma unroll
    for (int ks = 0; ks < 4; ++ks) {
      b0[ks] = *reinterpret_cast<const float4*>(rp + ks * 128);
      b1[ks] = *reinterpret_cast<const float4*>(rp + ks * 128 + 16);
    }
    lab = flabels[r];
  };

  auto MINMAX = [&](const bf8_t (&bfrag)[4], int t, int labj) {
    const int j = rowbase + t * 16 + l15;
#pragma unroll
    for (int mt = 0; mt < 4; ++mt) {
      f32x4 acc = {0.f, 0.f, 0.f, 0.f};
#pragma unroll
      for (int ks = 0; ks < 4; ++ks)
        acc = mfma_bf16(afrag[mt][ks], bfrag[ks], acc);
#pragma unroll
      for (int rr = 0; rr < 4; ++rr) {
        const float s    = acc[rr];
        const int   m    = meta[mt][rr];
        const bool same  = (labj == (m & 1023));
        const bool self  = (j == (m >> 10));
        minpos[mt][rr] = fminf(minpos[mt][rr], (same && !self) ? s : FLT_BIG);
        maxneg[mt][rr] = fmaxf(maxneg[mt][rr], same ? -FLT_BIG : s);
      }
    }
  };

  // depth-2 software pipeline over 10 tiles, two NAMED buffers (static regs)
  float4 a0[4], a1[4], b0[4], b1[4];
  int labA, labB;
  LOADT(0, a0, a1, labA);
  LOADT(1, b0, b1, labB);

#pragma unroll
  for (int tp = 0; tp < NT; tp += 2) {
    // even tile tp: cvt consumes buffer A (waits its loads), then refill A
    bf8_t bfA[4];
#pragma unroll
    for (int ks = 0; ks < 4; ++ks) bfA[ks] = pack8(a0[ks], a1[ks]);
    const int ljA = labA;
    if (tp + 2 < NT) LOADT(tp + 2, a0, a1, labA);   // WAR: ordered after cvt
    MINMAX(bfA, tp, ljA);

    // odd tile tp+1: same with buffer B
    bf8_t bfB[4];
#pragma unroll
    for (int ks = 0; ks < 4; ++ks) bfB[ks] = pack8(b0[ks], b1[ks]);
    const int ljB = labB;
    if (tp + 3 < NT) LOADT(tp + 3, b0, b1, labB);
    MINMAX(bfB, tp + 1, ljB);
  }

  // Reduce over the 16 cols held across each 16-lane group; coalesced write
#pragma unroll
  for (int mt = 0; mt < 4; ++mt)
#pragma unroll
    for (int rr = 0; rr < 4; ++rr) {
      float mp = minpos[mt][rr], mn = maxneg[mt][rr];
#pragma unroll
      for (int m = 1; m < 16; m <<= 1) {
        mp = fminf(mp, __shfl_xor(mp, m, 64));
        mn = fmaxf(mn, __shfl_xor(mn, m, 64));
      }
      if (l15 == 0) {
        const int row = m0 + mt * 16 + lg * 4 + rr;
        ppos[blk * NBATCH + row] = mp;   // [blk][row]: contiguous per block
        pneg[blk * NBATCH + row] = mn;
      }
    }
}

// Kernel 2: one block per batch row; fold GRID partials (L2-resident), hinge,
// atomic mean-accumulate into out[0] (zeroed by K1 block 0).
__global__ __launch_bounds__(256) void triplet_reduce(
    const float* __restrict__ ppos, const float* __restrict__ pneg,
    float* __restrict__ out)
{
  const int r = blockIdx.x;
  const int t = threadIdx.x;
  float mp = FLT_BIG, mn = -FLT_BIG;
  for (int b = t; b < GRID; b += 256) {
    mp = fminf(mp, ppos[b * NBATCH + r]);
    mn = fmaxf(mn, pneg[b * NBATCH + r]);
  }
#pragma unroll
  for (int m = 1; m < 64; m <<= 1) {
    mp = fminf(mp, __shfl_xor(mp, m, 64));
    mn = fmaxf(mn, __shfl_xor(mn, m, 64));
  }
  __shared__ float smp[4], smn[4];
  if ((t & 63) == 0) { smp[t >> 6] = mp; smn[t >> 6] = mn; }
  __syncthreads();
  if (t == 0) {
    mp = fminf(fminf(smp[0], smp[1]), fminf(smp[2], smp[3]));
    mn = fmaxf(fmaxf(smn[0], smn[1]), fmaxf(smn[2], smn[3]));
    float loss = mn - mp + MARGIN_F;
    loss = loss > 0.f ? loss : 0.f;
    atomicAdd(out, loss * (1.0f / NBATCH));
  }
}

extern "C" void kernel_launch(void* const* d_in, const int* in_sizes, int n_in,
                              void* d_out, int out_size, void* d_ws, size_t ws_size,
                              hipStream_t stream) {
  const float* inputs   = (const float*)d_in[0];
  const float* features = (const float*)d_in[1];
  const int*   targets  = (const int*)d_in[2];
  const int*   flabels  = (const int*)d_in[3];
  const int*   idx      = (const int*)d_in[4];
  float* out  = (float*)d_out;
  float* ppos = (float*)d_ws;                 // [GRID][256]
  float* pneg = ppos + (size_t)GRID * NBATCH; // [GRID][256]  (~1.28 MB total)

  triplet_partial<<<GRID, 256, 0, stream>>>(inputs, features, targets, flabels, idx, ppos, pneg, out);
  triplet_reduce<<<NBATCH, 256, 0, stream>>>(ppos, pneg, out);
}

// Round 11
// 44.744 us; speedup vs baseline: 1.6669x; 1.6669x over previous
//
#include <hip/hip_runtime.h>

#define NFEAT   100000
#define NBATCH  256
#define DIM     128
#define MARGIN_F 0.5f
#define GRID    1250                      // blocks; 1250*80 = 100000 exactly
#define RPB     80                        // feature rows per block
#define NTILE   5                         // 16-row tiles per block
#define BBYTES  (RPB * DIM * 4)           // 40 KiB staged B per block
#define FLT_BIG 3.402823466e+38f

typedef __bf16 bf8_t  __attribute__((ext_vector_type(8)));
typedef short  sh8_t  __attribute__((ext_vector_type(8)));
typedef float  f32x4  __attribute__((ext_vector_type(4)));

// f32 -> bf16 native cast: compiler emits v_cvt_pk_bf16_f32 pairs (RTNE).
__device__ __forceinline__ bf8_t pack8(float4 v0, float4 v1) {
  bf8_t r;
  r[0] = (__bf16)v0.x; r[1] = (__bf16)v0.y; r[2] = (__bf16)v0.z; r[3] = (__bf16)v0.w;
  r[4] = (__bf16)v1.x; r[5] = (__bf16)v1.y; r[6] = (__bf16)v1.z; r[7] = (__bf16)v1.w;
  return r;
}

// MFMA dispatch: works whether the builtin takes bf16-vectors or short-vectors
template <typename VA, typename VC>
__device__ __forceinline__ auto mfma_sel(VA a, VA b, VC c, int)
    -> decltype(__builtin_amdgcn_mfma_f32_16x16x32_bf16(a, b, c, 0, 0, 0)) {
  return __builtin_amdgcn_mfma_f32_16x16x32_bf16(a, b, c, 0, 0, 0);
}
template <typename VA, typename VC>
__device__ __forceinline__ VC mfma_sel(VA a, VA b, VC c, long) {
  return __builtin_amdgcn_mfma_f32_16x16x32_bf16(
      __builtin_bit_cast(sh8_t, a), __builtin_bit_cast(sh8_t, b), c, 0, 0, 0);
}
__device__ __forceinline__ f32x4 mfma_bf16(bf8_t a, bf8_t b, f32x4 c) {
  return mfma_sel(a, b, c, 0);
}

#if defined(__has_builtin)
#if __has_builtin(__builtin_amdgcn_global_load_lds)
#define HAVE_GLLDS 1
#endif
#endif

// 16B global -> LDS async DMA (no VGPR round-trip; counted by vmcnt).
__device__ __forceinline__ void stage16(const char* g, char* l) {
#ifdef HAVE_GLLDS
  __builtin_amdgcn_global_load_lds(
      (const __attribute__((address_space(1))) unsigned int*)g,
      (__attribute__((address_space(3))) unsigned int*)l, 16, 0, 0);
#else
  *reinterpret_cast<float4*>(l) = *reinterpret_cast<const float4*>(g);
#endif
}

// Kernel 1: fused GEMM + masked min/max partial reduction.
// R11: BURST-STAGE, BARRIER-ONCE. Diagnosis across R4-R10: every structure
// was latency-bound at 0.3-1.2 TB/s delivery because loads never pile up --
// per-iteration barriers made issue bursty, and reg-prefetch variants lost
// their pipelines to VGPR-pressure load-sinking. Here the block issues ALL
// 40 KB of its B-stage DMAs back-to-back (5 insts/thread; ~80 KB in flight
// per CU with 2 blocks/CU => Little's-law demand far above supply => the
// fetch stream is finally bandwidth-bound), then ONE __syncthreads() (the
// only vmcnt(0) drain), then a barrier-free compute loop reading LDS.
// 1250 blocks x 512 thr (8 waves x 2 M-tiles of 16 batch rows); block owns
// 80 contiguous feature rows (1250*80 = 100000, no tail, no masking).
// B XOR-swizzled via pre-swizzled DMA SOURCE (linear LDS dest, rule 21);
// reads undo it (byte ^= (row&7)<<4): 16-way bank conflict -> 2-way (free).
// MFMA 16x16x32 layouts (guide §3, m89/m91-verified):
//   A: lane l holds A[m0 + (l&15)][k0 + (l>>4)*8 + e]
//   B: lane l holds B[k0 + (l>>4)*8 + e][j0 + (l&15)]   (= features[j][k])
//   D: lane l reg r = sim[m0 + (l>>4)*4 + r][j0 + (l&15)]
__global__ __launch_bounds__(512, 4) void triplet_partial(
    const float* __restrict__ inputs, const float* __restrict__ features,
    const int* __restrict__ targets, const int* __restrict__ flabels,
    const int* __restrict__ idx,
    float* __restrict__ ppos, float* __restrict__ pneg,
    float* __restrict__ out)
{
  __shared__ char sB[BBYTES];          // 40 KiB: this block's 80 feature rows

  const int tid  = threadIdx.x;
  const int lane = tid & 63;
  const int wv   = tid >> 6;      // 0..7
  const int l15  = lane & 15;
  const int lg   = lane >> 4;     // 0..3
  const int m0   = wv * 32;
  const int blk  = blockIdx.x;
  const int rowbase = blk * RPB;  // first feature row of this block

  if (blk == 0 && tid == 0) out[0] = 0.0f;   // K2 accumulates atomically

  // ---- 1) burst-stage ALL of B first: maximal DMAs in flight immediately.
  // Linear LDS dest (uniform base + lane*16), pre-swizzled global source.
#pragma unroll
  for (int i = 0; i < NTILE; ++i) {
    const int p    = i * 8192 + tid * 16;       // LDS byte offset
    const int prow = p >> 9;                    // 0..79
    const int scol = (p & 511) ^ ((prow & 7) << 4);
    stage16((const char*)features + (size_t)(rowbase + prow) * 512 + scol,
            &sB[p]);
  }

  // ---- 2) A fragments (per-M-tile staging: <=8 float4 live; cvt implicitly
  // completes after the older DMAs -- harmless, the barrier waits for them
  // anyway). 2 M-tiles of 16 batch rows per wave.
  bf8_t afrag[2][4];
#pragma unroll
  for (int mt = 0; mt < 2; ++mt) {
    const float* ap = inputs + (m0 + mt * 16 + l15) * DIM;
    float4 v0[4], v1[4];
#pragma unroll
    for (int ks = 0; ks < 4; ++ks) {
      const int k = ks * 32 + lg * 8;
      v0[ks] = *reinterpret_cast<const float4*>(ap + k);
      v1[ks] = *reinterpret_cast<const float4*>(ap + k + 4);
    }
#pragma unroll
    for (int ks = 0; ks < 4; ++ks)
      afrag[mt][ks] = pack8(v0[ks], v1[ks]);
  }

  // ---- 3) labels for the 5 tiles this lane will see (l15 picks the row)
  int lab[NTILE];
#pragma unroll
  for (int t = 0; t < NTILE; ++t)
    lab[t] = flabels[rowbase + t * 16 + l15];

  // ---- 4) packed row metadata: meta = (self_gallery_row << 10) | target
  int meta[2][4];
#pragma unroll
  for (int mt = 0; mt < 2; ++mt)
#pragma unroll
    for (int rr = 0; rr < 4; ++rr) {
      const int row = m0 + mt * 16 + lg * 4 + rr;
      meta[mt][rr] = (idx[row] << 10) | targets[row];
    }

  float minpos[2][4], maxneg[2][4];
#pragma unroll
  for (int mt = 0; mt < 2; ++mt)
#pragma unroll
    for (int rr = 0; rr < 4; ++rr) { minpos[mt][rr] = FLT_BIG; maxneg[mt][rr] = -FLT_BIG; }

  __syncthreads();   // the ONE drain: all DMAs landed, B fully in LDS

  // ---- 5) barrier-free compute: 5 tiles from LDS
  const int swz = (l15 & 7) << 4;
#pragma unroll
  for (int t = 0; t < NTILE; ++t) {
    const char* rbase = &sB[(t * 16 + l15) * 512];
    const int   j     = rowbase + t * 16 + l15;
    const int   labj  = lab[t];

    f32x4 acc0 = {0.f, 0.f, 0.f, 0.f};
    f32x4 acc1 = {0.f, 0.f, 0.f, 0.f};
#pragma unroll
    for (int ks = 0; ks < 4; ++ks) {
      const int o = ks * 128 + lg * 32;
      float4 v0 = *reinterpret_cast<const float4*>(rbase + ((o)      ^ swz));
      float4 v1 = *reinterpret_cast<const float4*>(rbase + ((o + 16) ^ swz));
      bf8_t bf = pack8(v0, v1);
      acc0 = mfma_bf16(afrag[0][ks], bf, acc0);
      acc1 = mfma_bf16(afrag[1][ks], bf, acc1);
    }

#pragma unroll
    for (int rr = 0; rr < 4; ++rr) {
      {
        const int   m    = meta[0][rr];
        const bool same  = (labj == (m & 1023));
        const bool self  = (j == (m >> 10));
        minpos[0][rr] = fminf(minpos[0][rr], (same && !self) ? acc0[rr] : FLT_BIG);
        maxneg[0][rr] = fmaxf(maxneg[0][rr], same ? -FLT_BIG : acc0[rr]);
      }
      {
        const int   m    = meta[1][rr];
        const bool same  = (labj == (m & 1023));
        const bool self  = (j == (m >> 10));
        minpos[1][rr] = fminf(minpos[1][rr], (same && !self) ? acc1[rr] : FLT_BIG);
        maxneg[1][rr] = fmaxf(maxneg[1][rr], same ? -FLT_BIG : acc1[rr]);
      }
    }
  }

  // ---- 6) reduce over the 16 cols held across each 16-lane group;
  // TRANSPOSED partials ppos[row][blk] so K2 reads coalesce.
#pragma unroll
  for (int mt = 0; mt < 2; ++mt)
#pragma unroll
    for (int rr = 0; rr < 4; ++rr) {
      float mp = minpos[mt][rr], mn = maxneg[mt][rr];
#pragma unroll
      for (int m = 1; m < 16; m <<= 1) {
        mp = fminf(mp, __shfl_xor(mp, m, 64));
        mn = fmaxf(mn, __shfl_xor(mn, m, 64));
      }
      if (l15 == 0) {
        const int row = m0 + mt * 16 + lg * 4 + rr;
        ppos[row * GRID + blk] = mp;
        pneg[row * GRID + blk] = mn;
      }
    }
}

// Kernel 2: one block per batch row; coalesced fold of GRID partials
// (L2-resident), hinge, atomic mean-accumulate into out[0] (zeroed by K1).
__global__ __launch_bounds__(256) void triplet_reduce(
    const float* __restrict__ ppos, const float* __restrict__ pneg,
    float* __restrict__ out)
{
  const int r = blockIdx.x;
  const int t = threadIdx.x;
  float mp = FLT_BIG, mn = -FLT_BIG;
  for (int b = t; b < GRID; b += 256) {
    mp = fminf(mp, ppos[r * GRID + b]);
    mn = fmaxf(mn, pneg[r * GRID + b]);
  }
#pragma unroll
  for (int m = 1; m < 64; m <<= 1) {
    mp = fminf(mp, __shfl_xor(mp, m, 64));
    mn = fmaxf(mn, __shfl_xor(mn, m, 64));
  }
  __shared__ float smp[4], smn[4];
  if ((t & 63) == 0) { smp[t >> 6] = mp; smn[t >> 6] = mn; }
  __syncthreads();
  if (t == 0) {
    mp = fminf(fminf(smp[0], smp[1]), fminf(smp[2], smp[3]));
    mn = fmaxf(fmaxf(smn[0], smn[1]), fmaxf(smn[2], smn[3]));
    float loss = mn - mp + MARGIN_F;
    loss = loss > 0.f ? loss : 0.f;
    atomicAdd(out, loss * (1.0f / NBATCH));
  }
}

extern "C" void kernel_launch(void* const* d_in, const int* in_sizes, int n_in,
                              void* d_out, int out_size, void* d_ws, size_t ws_size,
                              hipStream_t stream) {
  const float* inputs   = (const float*)d_in[0];
  const float* features = (const float*)d_in[1];
  const int*   targets  = (const int*)d_in[2];
  const int*   flabels  = (const int*)d_in[3];
  const int*   idx      = (const int*)d_in[4];
  float* out  = (float*)d_out;
  float* ppos = (float*)d_ws;                 // [256][GRID]
  float* pneg = ppos + (size_t)NBATCH * GRID; // [256][GRID]  (~2.56 MB total)

  triplet_partial<<<GRID, 512, 0, stream>>>(inputs, features, targets, flabels, idx, ppos, pneg, out);
  triplet_reduce<<<NBATCH, 256, 0, stream>>>(ppos, pneg, out);
}

// Round 12
// 43.088 us; speedup vs baseline: 1.7310x; 1.0384x over previous
//
#include <hip/hip_runtime.h>

#define NFEAT   100000
#define NBATCH  256
#define DIM     128
#define MARGIN_F 0.5f
#define GRID    1250                      // blocks; 1250*80 = 100000 exactly
#define RPB     80                        // feature rows per block
#define NTILE   5                         // 16-row tiles per block
#define BBYTES  (RPB * DIM * 4)           // 40 KiB staged B per block
#define FLT_BIG 3.402823466e+38f

typedef __bf16 bf8_t  __attribute__((ext_vector_type(8)));
typedef short  sh8_t  __attribute__((ext_vector_type(8)));
typedef float  f32x4  __attribute__((ext_vector_type(4)));

// f32 -> bf16 native cast: compiler emits v_cvt_pk_bf16_f32 pairs (RTNE).
__device__ __forceinline__ bf8_t pack8(float4 v0, float4 v1) {
  bf8_t r;
  r[0] = (__bf16)v0.x; r[1] = (__bf16)v0.y; r[2] = (__bf16)v0.z; r[3] = (__bf16)v0.w;
  r[4] = (__bf16)v1.x; r[5] = (__bf16)v1.y; r[6] = (__bf16)v1.z; r[7] = (__bf16)v1.w;
  return r;
}

// MFMA dispatch: works whether the builtin takes bf16-vectors or short-vectors
template <typename VA, typename VC>
__device__ __forceinline__ auto mfma_sel(VA a, VA b, VC c, int)
    -> decltype(__builtin_amdgcn_mfma_f32_16x16x32_bf16(a, b, c, 0, 0, 0)) {
  return __builtin_amdgcn_mfma_f32_16x16x32_bf16(a, b, c, 0, 0, 0);
}
template <typename VA, typename VC>
__device__ __forceinline__ VC mfma_sel(VA a, VA b, VC c, long) {
  return __builtin_amdgcn_mfma_f32_16x16x32_bf16(
      __builtin_bit_cast(sh8_t, a), __builtin_bit_cast(sh8_t, b), c, 0, 0, 0);
}
__device__ __forceinline__ f32x4 mfma_bf16(bf8_t a, bf8_t b, f32x4 c) {
  return mfma_sel(a, b, c, 0);
}

#if defined(__has_builtin)
#if __has_builtin(__builtin_amdgcn_global_load_lds)
#define HAVE_GLLDS 1
#endif
#endif

// 16B global -> LDS async DMA (no VGPR round-trip; counted by vmcnt).
__device__ __forceinline__ void stage16(const char* g, char* l) {
#ifdef HAVE_GLLDS
  __builtin_amdgcn_global_load_lds(
      (const __attribute__((address_space(1))) unsigned int*)g,
      (__attribute__((address_space(3))) unsigned int*)l, 16, 0, 0);
#else
  *reinterpret_cast<float4*>(l) = *reinterpret_cast<const float4*>(g);
#endif
}

// Kernel 1: fused GEMM + masked min/max partial reduction.
// R11 structure: BURST-STAGE, BARRIER-ONCE. Block issues ALL 40 KB of its
// B-stage DMAs back-to-back, then ONE __syncthreads() (the only vmcnt(0)
// drain), then a barrier-free compute loop reading LDS.
// R12 change: __launch_bounds__(512, 2). The (512,4)=128-reg cap forced
// ~18 MB of scratch spills (VGPR_Count 56, WRITE_SIZE 20.4 MB) whose VMEM
// waits serialized against the DMA queue -- same disease as R5/R6; R7
// proved (512,2) -> VGPR 76-88, zero scratch. DO NOT re-tighten this bound.
// 1250 blocks x 512 thr (8 waves x 2 M-tiles of 16 batch rows); block owns
// 80 contiguous feature rows (1250*80 = 100000, no tail, no masking).
// B XOR-swizzled via pre-swizzled DMA SOURCE (linear LDS dest, rule 21);
// reads undo it (byte ^= (row&7)<<4): 16-way bank conflict -> 2-way (free).
// MFMA 16x16x32 layouts (guide §3, m89/m91-verified):
//   A: lane l holds A[m0 + (l&15)][k0 + (l>>4)*8 + e]
//   B: lane l holds B[k0 + (l>>4)*8 + e][j0 + (l&15)]   (= features[j][k])
//   D: lane l reg r = sim[m0 + (l>>4)*4 + r][j0 + (l&15)]
__global__ __launch_bounds__(512, 2) void triplet_partial(
    const float* __restrict__ inputs, const float* __restrict__ features,
    const int* __restrict__ targets, const int* __restrict__ flabels,
    const int* __restrict__ idx,
    float* __restrict__ ppos, float* __restrict__ pneg,
    float* __restrict__ out)
{
  __shared__ char sB[BBYTES];          // 40 KiB: this block's 80 feature rows

  const int tid  = threadIdx.x;
  const int lane = tid & 63;
  const int wv   = tid >> 6;      // 0..7
  const int l15  = lane & 15;
  const int lg   = lane >> 4;     // 0..3
  const int m0   = wv * 32;
  const int blk  = blockIdx.x;
  const int rowbase = blk * RPB;  // first feature row of this block

  if (blk == 0 && tid == 0) out[0] = 0.0f;   // K2 accumulates atomically

  // ---- 1) burst-stage ALL of B first: maximal DMAs in flight immediately.
  // Linear LDS dest (uniform base + lane*16), pre-swizzled global source.
#pragma unroll
  for (int i = 0; i < NTILE; ++i) {
    const int p    = i * 8192 + tid * 16;       // LDS byte offset
    const int prow = p >> 9;                    // 0..79
    const int scol = (p & 511) ^ ((prow & 7) << 4);
    stage16((const char*)features + (size_t)(rowbase + prow) * 512 + scol,
            &sB[p]);
  }

  // ---- 2) A fragments (per-M-tile staging: <=8 float4 live; cvt implicitly
  // completes after the older DMAs -- harmless, the barrier waits for them
  // anyway). 2 M-tiles of 16 batch rows per wave.
  bf8_t afrag[2][4];
#pragma unroll
  for (int mt = 0; mt < 2; ++mt) {
    const float* ap = inputs + (m0 + mt * 16 + l15) * DIM;
    float4 v0[4], v1[4];
#pragma unroll
    for (int ks = 0; ks < 4; ++ks) {
      const int k = ks * 32 + lg * 8;
      v0[ks] = *reinterpret_cast<const float4*>(ap + k);
      v1[ks] = *reinterpret_cast<const float4*>(ap + k + 4);
    }
#pragma unroll
    for (int ks = 0; ks < 4; ++ks)
      afrag[mt][ks] = pack8(v0[ks], v1[ks]);
  }

  // ---- 3) labels for the 5 tiles this lane will see (l15 picks the row)
  int lab[NTILE];
#pragma unroll
  for (int t = 0; t < NTILE; ++t)
    lab[t] = flabels[rowbase + t * 16 + l15];

  // ---- 4) packed row metadata: meta = (self_gallery_row << 10) | target
  int meta[2][4];
#pragma unroll
  for (int mt = 0; mt < 2; ++mt)
#pragma unroll
    for (int rr = 0; rr < 4; ++rr) {
      const int row = m0 + mt * 16 + lg * 4 + rr;
      meta[mt][rr] = (idx[row] << 10) | targets[row];
    }

  float minpos[2][4], maxneg[2][4];
#pragma unroll
  for (int mt = 0; mt < 2; ++mt)
#pragma unroll
    for (int rr = 0; rr < 4; ++rr) { minpos[mt][rr] = FLT_BIG; maxneg[mt][rr] = -FLT_BIG; }

  __syncthreads();   // the ONE drain: all DMAs landed, B fully in LDS

  // ---- 5) barrier-free compute: 5 tiles from LDS
  const int swz = (l15 & 7) << 4;
#pragma unroll
  for (int t = 0; t < NTILE; ++t) {
    const char* rbase = &sB[(t * 16 + l15) * 512];
    const int   j     = rowbase + t * 16 + l15;
    const int   labj  = lab[t];

    f32x4 acc0 = {0.f, 0.f, 0.f, 0.f};
    f32x4 acc1 = {0.f, 0.f, 0.f, 0.f};
#pragma unroll
    for (int ks = 0; ks < 4; ++ks) {
      const int o = ks * 128 + lg * 32;
      float4 v0 = *reinterpret_cast<const float4*>(rbase + ((o)      ^ swz));
      float4 v1 = *reinterpret_cast<const float4*>(rbase + ((o + 16) ^ swz));
      bf8_t bf = pack8(v0, v1);
      acc0 = mfma_bf16(afrag[0][ks], bf, acc0);
      acc1 = mfma_bf16(afrag[1][ks], bf, acc1);
    }

#pragma unroll
    for (int rr = 0; rr < 4; ++rr) {
      {
        const int   m    = meta[0][rr];
        const bool same  = (labj == (m & 1023));
        const bool self  = (j == (m >> 10));
        minpos[0][rr] = fminf(minpos[0][rr], (same && !self) ? acc0[rr] : FLT_BIG);
        maxneg[0][rr] = fmaxf(maxneg[0][rr], same ? -FLT_BIG : acc0[rr]);
      }
      {
        const int   m    = meta[1][rr];
        const bool same  = (labj == (m & 1023));
        const bool self  = (j == (m >> 10));
        minpos[1][rr] = fminf(minpos[1][rr], (same && !self) ? acc1[rr] : FLT_BIG);
        maxneg[1][rr] = fmaxf(maxneg[1][rr], same ? -FLT_BIG : acc1[rr]);
      }
    }
  }

  // ---- 6) reduce over the 16 cols held across each 16-lane group;
  // TRANSPOSED partials ppos[row][blk] so K2 reads coalesce.
#pragma unroll
  for (int mt = 0; mt < 2; ++mt)
#pragma unroll
    for (int rr = 0; rr < 4; ++rr) {
      float mp = minpos[mt][rr], mn = maxneg[mt][rr];
#pragma unroll
      for (int m = 1; m < 16; m <<= 1) {
        mp = fminf(mp, __shfl_xor(mp, m, 64));
        mn = fmaxf(mn, __shfl_xor(mn, m, 64));
      }
      if (l15 == 0) {
        const int row = m0 + mt * 16 + lg * 4 + rr;
        ppos[row * GRID + blk] = mp;
        pneg[row * GRID + blk] = mn;
      }
    }
}

// Kernel 2: one block per batch row; coalesced fold of GRID partials
// (L2-resident), hinge, atomic mean-accumulate into out[0] (zeroed by K1).
__global__ __launch_bounds__(256) void triplet_reduce(
    const float* __restrict__ ppos, const float* __restrict__ pneg,
    float* __restrict__ out)
{
  const int r = blockIdx.x;
  const int t = threadIdx.x;
  float mp = FLT_BIG, mn = -FLT_BIG;
  for (int b = t; b < GRID; b += 256) {
    mp = fminf(mp, ppos[r * GRID + b]);
    mn = fmaxf(mn, pneg[r * GRID + b]);
  }
#pragma unroll
  for (int m = 1; m < 64; m <<= 1) {
    mp = fminf(mp, __shfl_xor(mp, m, 64));
    mn = fmaxf(mn, __shfl_xor(mn, m, 64));
  }
  __shared__ float smp[4], smn[4];
  if ((t & 63) == 0) { smp[t >> 6] = mp; smn[t >> 6] = mn; }
  __syncthreads();
  if (t == 0) {
    mp = fminf(fminf(smp[0], smp[1]), fminf(smp[2], smp[3]));
    mn = fmaxf(fmaxf(smn[0], smn[1]), fmaxf(smn[2], smn[3]));
    float loss = mn - mp + MARGIN_F;
    loss = loss > 0.f ? loss : 0.f;
    atomicAdd(out, loss * (1.0f / NBATCH));
  }
}

extern "C" void kernel_launch(void* const* d_in, const int* in_sizes, int n_in,
                              void* d_out, int out_size, void* d_ws, size_t ws_size,
                              hipStream_t stream) {
  const float* inputs   = (const float*)d_in[0];
  const float* features = (const float*)d_in[1];
  const int*   targets  = (const int*)d_in[2];
  const int*   flabels  = (const int*)d_in[3];
  const int*   idx      = (const int*)d_in[4];
  float* out  = (float*)d_out;
  float* ppos = (float*)d_ws;                 // [256][GRID]
  float* pneg = ppos + (size_t)NBATCH * GRID; // [256][GRID]  (~2.56 MB total)

  triplet_partial<<<GRID, 512, 0, stream>>>(inputs, features, targets, flabels, idx, ppos, pneg, out);
  triplet_reduce<<<NBATCH, 256, 0, stream>>>(ppos, pneg, out);
}

// Round 13
// 43.060 us; speedup vs baseline: 1.7321x; 1.0007x over previous
//
#include <hip/hip_runtime.h>

#define NFEAT   100000
#define NBATCH  256
#define DIM     128
#define MARGIN_F 0.5f
#define GRID    1250                      // blocks; 1250*80 = 100000 exactly
#define RPB     80                        // feature rows per block
#define NTILE   5                         // 16-row tiles per block
#define BBYTES  (RPB * DIM * 4)           // 40 KiB staged B per block
#define FLT_BIG 3.402823466e+38f

typedef __bf16 bf8_t  __attribute__((ext_vector_type(8)));
typedef short  sh8_t  __attribute__((ext_vector_type(8)));
typedef float  f32x4  __attribute__((ext_vector_type(4)));

// f32 -> bf16 native cast: compiler emits v_cvt_pk_bf16_f32 pairs (RTNE).
__device__ __forceinline__ bf8_t pack8(float4 v0, float4 v1) {
  bf8_t r;
  r[0] = (__bf16)v0.x; r[1] = (__bf16)v0.y; r[2] = (__bf16)v0.z; r[3] = (__bf16)v0.w;
  r[4] = (__bf16)v1.x; r[5] = (__bf16)v1.y; r[6] = (__bf16)v1.z; r[7] = (__bf16)v1.w;
  return r;
}

// MFMA dispatch: works whether the builtin takes bf16-vectors or short-vectors
template <typename VA, typename VC>
__device__ __forceinline__ auto mfma_sel(VA a, VA b, VC c, int)
    -> decltype(__builtin_amdgcn_mfma_f32_16x16x32_bf16(a, b, c, 0, 0, 0)) {
  return __builtin_amdgcn_mfma_f32_16x16x32_bf16(a, b, c, 0, 0, 0);
}
template <typename VA, typename VC>
__device__ __forceinline__ VC mfma_sel(VA a, VA b, VC c, long) {
  return __builtin_amdgcn_mfma_f32_16x16x32_bf16(
      __builtin_bit_cast(sh8_t, a), __builtin_bit_cast(sh8_t, b), c, 0, 0, 0);
}
__device__ __forceinline__ f32x4 mfma_bf16(bf8_t a, bf8_t b, f32x4 c) {
  return mfma_sel(a, b, c, 0);
}

#if defined(__has_builtin)
#if __has_builtin(__builtin_amdgcn_global_load_lds)
#define HAVE_GLLDS 1
#endif
#endif

// 16B global -> LDS async DMA (no VGPR round-trip; counted by vmcnt).
__device__ __forceinline__ void stage16(const char* g, char* l) {
#ifdef HAVE_GLLDS
  __builtin_amdgcn_global_load_lds(
      (const __attribute__((address_space(1))) unsigned int*)g,
      (__attribute__((address_space(3))) unsigned int*)l, 16, 0, 0);
#else
  *reinterpret_cast<float4*>(l) = *reinterpret_cast<const float4*>(g);
#endif
}

// Kernel 1: fused GEMM + masked min/max partial reduction.
// Structure (R11): BURST-STAGE, BARRIER-ONCE. Block issues ALL 40 KB of its
// B-stage DMAs back-to-back, then ONE __syncthreads() (the only vmcnt(0)
// drain), then a barrier-free compute loop reading LDS.
// R13 change: partials back to CONTIGUOUS [blk][row]. The R11/R12 transposed
// [row][blk] layout had 16 blocks (~8 XCDs) writing each 64B line -> cross-XCD
// dirty-line ping-pong = 20.4 MB WRITE_SIZE (vs 2.56 MB of data) and a
// serialized coherence tail. R5-R8 proved [blk][row] writes 1.25 MB. ERRATA:
// R11's "spill" diagnosis was wrong -- VGPR=64 fits this kernel; the 20 MB
// was always the write scatter. DO NOT transpose the partial layout again.
// 1250 blocks x 512 thr (8 waves x 2 M-tiles of 16 batch rows); block owns
// 80 contiguous feature rows (1250*80 = 100000, no tail, no masking).
// B XOR-swizzled via pre-swizzled DMA SOURCE (linear LDS dest, rule 21);
// reads undo it (byte ^= (row&7)<<4): 16-way bank conflict -> 2-way (free).
// MFMA 16x16x32 layouts (guide §3, m89/m91-verified):
//   A: lane l holds A[m0 + (l&15)][k0 + (l>>4)*8 + e]
//   B: lane l holds B[k0 + (l>>4)*8 + e][j0 + (l&15)]   (= features[j][k])
//   D: lane l reg r = sim[m0 + (l>>4)*4 + r][j0 + (l&15)]
__global__ __launch_bounds__(512, 2) void triplet_partial(
    const float* __restrict__ inputs, const float* __restrict__ features,
    const int* __restrict__ targets, const int* __restrict__ flabels,
    const int* __restrict__ idx,
    float* __restrict__ ppos, float* __restrict__ pneg,
    float* __restrict__ out)
{
  __shared__ char sB[BBYTES];          // 40 KiB: this block's 80 feature rows

  const int tid  = threadIdx.x;
  const int lane = tid & 63;
  const int wv   = tid >> 6;      // 0..7
  const int l15  = lane & 15;
  const int lg   = lane >> 4;     // 0..3
  const int m0   = wv * 32;
  const int blk  = blockIdx.x;
  const int rowbase = blk * RPB;  // first feature row of this block

  if (blk == 0 && tid == 0) out[0] = 0.0f;   // K2 accumulates atomically

  // ---- 1) burst-stage ALL of B first: maximal DMAs in flight immediately.
  // Linear LDS dest (uniform base + lane*16), pre-swizzled global source.
#pragma unroll
  for (int i = 0; i < NTILE; ++i) {
    const int p    = i * 8192 + tid * 16;       // LDS byte offset
    const int prow = p >> 9;                    // 0..79
    const int scol = (p & 511) ^ ((prow & 7) << 4);
    stage16((const char*)features + (size_t)(rowbase + prow) * 512 + scol,
            &sB[p]);
  }

  // ---- 2) A fragments (per-M-tile staging: <=8 float4 live; cvt implicitly
  // completes after the older DMAs -- harmless, the barrier waits for them
  // anyway). 2 M-tiles of 16 batch rows per wave.
  bf8_t afrag[2][4];
#pragma unroll
  for (int mt = 0; mt < 2; ++mt) {
    const float* ap = inputs + (m0 + mt * 16 + l15) * DIM;
    float4 v0[4], v1[4];
#pragma unroll
    for (int ks = 0; ks < 4; ++ks) {
      const int k = ks * 32 + lg * 8;
      v0[ks] = *reinterpret_cast<const float4*>(ap + k);
      v1[ks] = *reinterpret_cast<const float4*>(ap + k + 4);
    }
#pragma unroll
    for (int ks = 0; ks < 4; ++ks)
      afrag[mt][ks] = pack8(v0[ks], v1[ks]);
  }

  // ---- 3) labels for the 5 tiles this lane will see (l15 picks the row)
  int lab[NTILE];
#pragma unroll
  for (int t = 0; t < NTILE; ++t)
    lab[t] = flabels[rowbase + t * 16 + l15];

  // ---- 4) packed row metadata: meta = (self_gallery_row << 10) | target
  int meta[2][4];
#pragma unroll
  for (int mt = 0; mt < 2; ++mt)
#pragma unroll
    for (int rr = 0; rr < 4; ++rr) {
      const int row = m0 + mt * 16 + lg * 4 + rr;
      meta[mt][rr] = (idx[row] << 10) | targets[row];
    }

  float minpos[2][4], maxneg[2][4];
#pragma unroll
  for (int mt = 0; mt < 2; ++mt)
#pragma unroll
    for (int rr = 0; rr < 4; ++rr) { minpos[mt][rr] = FLT_BIG; maxneg[mt][rr] = -FLT_BIG; }

  __syncthreads();   // the ONE drain: all DMAs landed, B fully in LDS

  // ---- 5) barrier-free compute: 5 tiles from LDS
  const int swz = (l15 & 7) << 4;
#pragma unroll
  for (int t = 0; t < NTILE; ++t) {
    const char* rbase = &sB[(t * 16 + l15) * 512];
    const int   j     = rowbase + t * 16 + l15;
    const int   labj  = lab[t];

    f32x4 acc0 = {0.f, 0.f, 0.f, 0.f};
    f32x4 acc1 = {0.f, 0.f, 0.f, 0.f};
#pragma unroll
    for (int ks = 0; ks < 4; ++ks) {
      const int o = ks * 128 + lg * 32;
      float4 v0 = *reinterpret_cast<const float4*>(rbase + ((o)      ^ swz));
      float4 v1 = *reinterpret_cast<const float4*>(rbase + ((o + 16) ^ swz));
      bf8_t bf = pack8(v0, v1);
      acc0 = mfma_bf16(afrag[0][ks], bf, acc0);
      acc1 = mfma_bf16(afrag[1][ks], bf, acc1);
    }

#pragma unroll
    for (int rr = 0; rr < 4; ++rr) {
      {
        const int   m    = meta[0][rr];
        const bool same  = (labj == (m & 1023));
        const bool self  = (j == (m >> 10));
        minpos[0][rr] = fminf(minpos[0][rr], (same && !self) ? acc0[rr] : FLT_BIG);
        maxneg[0][rr] = fmaxf(maxneg[0][rr], same ? -FLT_BIG : acc0[rr]);
      }
      {
        const int   m    = meta[1][rr];
        const bool same  = (labj == (m & 1023));
        const bool self  = (j == (m >> 10));
        minpos[1][rr] = fminf(minpos[1][rr], (same && !self) ? acc1[rr] : FLT_BIG);
        maxneg[1][rr] = fmaxf(maxneg[1][rr], same ? -FLT_BIG : acc1[rr]);
      }
    }
  }

  // ---- 6) reduce over the 16 cols held across each 16-lane group;
  // CONTIGUOUS per-block writes ppos[blk][row] (2 KB exclusive lines).
#pragma unroll
  for (int mt = 0; mt < 2; ++mt)
#pragma unroll
    for (int rr = 0; rr < 4; ++rr) {
      float mp = minpos[mt][rr], mn = maxneg[mt][rr];
#pragma unroll
      for (int m = 1; m < 16; m <<= 1) {
        mp = fminf(mp, __shfl_xor(mp, m, 64));
        mn = fmaxf(mn, __shfl_xor(mn, m, 64));
      }
      if (l15 == 0) {
        const int row = m0 + mt * 16 + lg * 4 + rr;
        ppos[blk * NBATCH + row] = mp;
        pneg[blk * NBATCH + row] = mn;
      }
    }
}

// Kernel 2: one block per batch row; fold GRID partials (L2-resident, strided
// reads), hinge, atomic mean-accumulate into out[0] (zeroed by K1 block 0).
__global__ __launch_bounds__(256) void triplet_reduce(
    const float* __restrict__ ppos, const float* __restrict__ pneg,
    float* __restrict__ out)
{
  const int r = blockIdx.x;
  const int t = threadIdx.x;
  float mp = FLT_BIG, mn = -FLT_BIG;
  for (int b = t; b < GRID; b += 256) {
    mp = fminf(mp, ppos[b * NBATCH + r]);
    mn = fmaxf(mn, pneg[b * NBATCH + r]);
  }
#pragma unroll
  for (int m = 1; m < 64; m <<= 1) {
    mp = fminf(mp, __shfl_xor(mp, m, 64));
    mn = fmaxf(mn, __shfl_xor(mn, m, 64));
  }
  __shared__ float smp[4], smn[4];
  if ((t & 63) == 0) { smp[t >> 6] = mp; smn[t >> 6] = mn; }
  __syncthreads();
  if (t == 0) {
    mp = fminf(fminf(smp[0], smp[1]), fminf(smp[2], smp[3]));
    mn = fmaxf(fmaxf(smn[0], smn[1]), fmaxf(smn[2], smn[3]));
    float loss = mn - mp + MARGIN_F;
    loss = loss > 0.f ? loss : 0.f;
    atomicAdd(out, loss * (1.0f / NBATCH));
  }
}

extern "C" void kernel_launch(void* const* d_in, const int* in_sizes, int n_in,
                              void* d_out, int out_size, void* d_ws, size_t ws_size,
                              hipStream_t stream) {
  const float* inputs   = (const float*)d_in[0];
  const float* features = (const float*)d_in[1];
  const int*   targets  = (const int*)d_in[2];
  const int*   flabels  = (const int*)d_in[3];
  const int*   idx      = (const int*)d_in[4];
  float* out  = (float*)d_out;
  float* ppos = (float*)d_ws;                 // [GRID][256]
  float* pneg = ppos + (size_t)GRID * NBATCH; // [GRID][256]  (~2.56 MB total)

  triplet_partial<<<GRID, 512, 0, stream>>>(inputs, features, targets, flabels, idx, ppos, pneg, out);
  triplet_reduce<<<NBATCH, 256, 0, stream>>>(ppos, pneg, out);
}